// Round 3
// baseline (108.979 us; speedup 1.0000x reference)
//
#include <hip/hip_runtime.h>
#include <hip/hip_bf16.h>

typedef __bf16 bf16x8 __attribute__((ext_vector_type(8)));
typedef float f32x16 __attribute__((ext_vector_type(16)));
typedef unsigned int u32x4 __attribute__((ext_vector_type(4)));
typedef unsigned short u16;

// Problem constants: T=16, N=128, D=512, M=4096, NT=2048, TEMP=0.1
// ws layout: zn bf16[4096*512] (4 MiB) | expsum f32[4096] | possum f32[4096]

// ---------------------------------------------------------------- normalize
// 1024 blocks x 256 threads; one wave per row, full-wave shfl_xor reduce,
// no LDS, no barrier. Also zeroes expsum.
__global__ void nrm_kernel(const float* __restrict__ z, u16* __restrict__ zn,
                           float* __restrict__ expsum) {
    int tid = threadIdx.x;
    int l = tid & 63, w = tid >> 6;
    int row = blockIdx.x * 4 + w;
    const float4* src = (const float4*)(z + row * 512);
    float4 v0 = src[l];
    float4 v1 = src[l + 64];
    float ss = v0.x * v0.x + v0.y * v0.y + v0.z * v0.z + v0.w * v0.w
             + v1.x * v1.x + v1.y * v1.y + v1.z * v1.z + v1.w * v1.w;
#pragma unroll
    for (int off = 32; off; off >>= 1) ss += __shfl_xor(ss, off, 64);
    float sc = 1.0f / fmaxf(sqrtf(ss), 1e-8f);   // matches ref clamp
    __hip_bfloat16 b0[4], b1[4];
    b0[0] = __float2bfloat16(v0.x * sc); b0[1] = __float2bfloat16(v0.y * sc);
    b0[2] = __float2bfloat16(v0.z * sc); b0[3] = __float2bfloat16(v0.w * sc);
    b1[0] = __float2bfloat16(v1.x * sc); b1[1] = __float2bfloat16(v1.y * sc);
    b1[2] = __float2bfloat16(v1.z * sc); b1[3] = __float2bfloat16(v1.w * sc);
    uint2 p0, p1;
    __builtin_memcpy(&p0, b0, 8);
    __builtin_memcpy(&p1, b1, 8);
    ((uint2*)(zn + row * 512))[l] = p0;
    ((uint2*)(zn + row * 512))[l + 64] = p1;
    int gi = blockIdx.x * 256 + tid;
    if (gi < 4096) expsum[gi] = 0.f;
}

// ------------------------------------------- symmetric GEMM (+pos tail)
// Blocks [0,528): triangular (ti<=tj) 128x128 tiles of the symmetric Gram.
//   4 waves/WG, wave owns 32 rows, A (32x512 bf16) resident in 128 VGPRs.
//   Col tiles of 32 staged via global_load_lds width=16: LDS dest is LINEAR
//   (rule #21), the XOR granule swizzle is applied to the per-lane GLOBAL
//   source address, so ds_read_b128 stays conflict-free with zero staging
//   VALU/VGPR and no ds_writes. Double-buffered, one barrier per col-tile;
//   the implicit vmcnt(0) drain sits after the 32-MFMA cluster.
//   Off-diag tiles: e_ij feeds expsum[i] (row reduce at end) AND expsum[j]
//   (atomic, symmetry). Diag tiles: rows only, true diagonal masked in the
//   aligned (wave==ct) sub-block.
// Blocks [528,656): pos work — 32x32 group Gram, possum[i] = 10*sum dot.
__global__ __launch_bounds__(256, 2) void gemm_kernel(const u16* __restrict__ zn,
                                                      float* __restrict__ expsum,
                                                      float* __restrict__ possum) {
    __shared__ u16 Bt[2][32 * 512];            // 64 KiB double buffer

    int tid = threadIdx.x;
    int wave = tid >> 6;
    int l = tid & 63;
    int m = l & 31, h = l >> 5;

    if (blockIdx.x >= 528) {       // ---------------- positives tail
        if (tid < 64) {
            int g = blockIdx.x - 528;
            int grow = (m < 16) ? (g * 16 + m) : (2048 + g * 16 + (m - 16));
            const u32x4* src = (const u32x4*)(zn + grow * 512);
            f32x16 acc = {};
#pragma unroll
            for (int kc = 0; kc < 32; ++kc) {
                bf16x8 f = __builtin_bit_cast(bf16x8, src[h + 2 * kc]);
                acc = __builtin_amdgcn_mfma_f32_32x32x16_bf16(f, f, acc, 0, 0, 0);
            }
#pragma unroll
            for (int r = 0; r < 16; ++r) {
                int rrow = (r & 3) + 8 * (r >> 2) + 4 * h;
                float v = (rrow == m) ? 0.f : acc[r];
                v += __shfl_xor(v, 1, 64);
                v += __shfl_xor(v, 2, 64);
                v += __shfl_xor(v, 4, 64);
                v += __shfl_xor(v, 8, 64);
                v += __shfl_xor(v, 16, 64);
                if (m == 0) {
                    int gr = (rrow < 16) ? (g * 16 + rrow) : (2048 + g * 16 + (rrow - 16));
                    possum[gr] = v * 10.0f;   // plain store; fin is a separate launch
                }
            }
        }
        return;
    }

    // triangular decode: tile row ti has 32-ti tiles (tj = ti..31)
    int b = blockIdx.x;
    int ti = 0;
    while (b >= 32 - ti) { b -= 32 - ti; ++ti; }
    int tj = ti + b;

    int rowbase = ti * 128 + wave * 32;
    int colbase = tj * 128;
    bool diag = (ti == tj);

    // A fragments, full K=512: row rowbase+m, k-granule h+2*kc
    u32x4 a[32];
    const u32x4* arow = (const u32x4*)(zn + (rowbase + m) * 512);
#pragma unroll
    for (int kc = 0; kc < 32; ++kc) a[kc] = arow[h + 2 * kc];

    float racc[16];
#pragma unroll
    for (int r = 0; r < 16; ++r) racc[r] = 0.f;

    // read geometry: LDS content at linear granule (c, t) is global granule
    // t^(c&7) of col c. Desired granule g=h+2*kc, kc=4*kg+q ->
    // byte = m*1024 + (h^sw0)*16 + (q^sw12)*32 + kg*128.
    int sw0 = m & 1, sw12 = (m >> 1) & 3;
    int rbyte[4];
#pragma unroll
    for (int q = 0; q < 4; ++q)
        rbyte[q] = m * 1024 + (h ^ sw0) * 16 + ((q ^ sw12) * 32);

    // stage: wave w covers cols c=w*8..w*8+7; global_load_lds writes lane l
    // -> linear granule l of col c; source granule l^(c&7) (both-sides rule).
#define STAGE(bufidx, cb)                                                          \
    {                                                                              \
        u16* buf_ = (u16*)Bt[bufidx];                                              \
        _Pragma("unroll")                                                          \
        for (int i_ = 0; i_ < 8; ++i_) {                                           \
            int cc_ = wave * 8 + i_;                                               \
            const u16* gsrc_ = zn + ((cb) + cc_) * 512 + ((l ^ (cc_ & 7)) * 8);    \
            __builtin_amdgcn_global_load_lds(                                      \
                (const __attribute__((address_space(1))) unsigned int*)gsrc_,      \
                (__attribute__((address_space(3))) unsigned int*)(buf_ + cc_ * 512), \
                16, 0, 0);                                                         \
        }                                                                          \
    }

    STAGE(0, colbase)
    __syncthreads();           // implicit vmcnt(0): tile 0 landed

    for (int ct = 0; ct < 4; ++ct) {
        if (ct < 3) STAGE((ct + 1) & 1, colbase + (ct + 1) * 32)
        const char* rb = (const char*)Bt[ct & 1];
        f32x16 acc = {};
        __builtin_amdgcn_s_setprio(1);
#pragma unroll
        for (int kg = 0; kg < 8; ++kg) {
#pragma unroll
            for (int q = 0; q < 4; ++q) {
                bf16x8 bf = *(const bf16x8*)(rb + rbyte[q] + kg * 128);
                acc = __builtin_amdgcn_mfma_f32_32x32x16_bf16(
                    __builtin_bit_cast(bf16x8, a[4 * kg + q]), bf, acc, 0, 0, 0);
            }
        }
        __builtin_amdgcn_s_setprio(0);

        if (diag && ct == wave) {  // aligned sub-block: mask true diagonal
#pragma unroll
            for (int r = 0; r < 16; ++r) {
                int rrow = (r & 3) + 8 * (r >> 2) + 4 * h;
                if (rrow != m) racc[r] += __builtin_exp2f(acc[r] * 14.426950408889634f);
            }
        } else {
            float csum = 0.f;
#pragma unroll
            for (int r = 0; r < 16; ++r) {
                float e = __builtin_exp2f(acc[r] * 14.426950408889634f);
                racc[r] += e;
                csum += e;
            }
            if (!diag) {           // symmetric contribution to the col rows
                csum += __shfl_xor(csum, 32, 64);   // combine the two k-halves
                if (h == 0) atomicAdd(&expsum[colbase + ct * 32 + m], csum);
            }
        }
        __syncthreads();           // next tile landed; current reads done
    }

    // row sums: reduce over the 32 cols held in lanes of each half
#pragma unroll
    for (int r = 0; r < 16; ++r) {
        float v = racc[r];
        v += __shfl_xor(v, 1, 64);
        v += __shfl_xor(v, 2, 64);
        v += __shfl_xor(v, 4, 64);
        v += __shfl_xor(v, 8, 64);
        v += __shfl_xor(v, 16, 64);
        if (m == 0) {
            int rrow = (r & 3) + 8 * (r >> 2) + 4 * h;
            atomicAdd(&expsum[rowbase + rrow], v);
        }
    }
}

// ---------------------------------------------------------------- finalize
__global__ void fin_kernel(const float* __restrict__ expsum,
                           const float* __restrict__ possum, float* __restrict__ out) {
    int tid = threadIdx.x;         // 1024
    float s = 0.f;
    for (int i = tid; i < 4096; i += 1024)
        s += __logf(expsum[i]) - possum[i] * (1.0f / 31.0f);
#pragma unroll
    for (int off = 32; off; off >>= 1) s += __shfl_down(s, off, 64);
    __shared__ float red[16];
    if ((tid & 63) == 0) red[tid >> 6] = s;
    __syncthreads();
    if (tid == 0) {
        float t = 0.f;
#pragma unroll
        for (int i = 0; i < 16; ++i) t += red[i];
        out[0] = t * (1.0f / 4096.0f);
    }
}

extern "C" void kernel_launch(void* const* d_in, const int* in_sizes, int n_in,
                              void* d_out, int out_size, void* d_ws, size_t ws_size,
                              hipStream_t stream) {
    const float* z = (const float*)d_in[0];
    // d_in[1] (done) is provably dead: positive_mask reduces to block-diag + eye.
    u16* zn = (u16*)d_ws;
    float* expsum = (float*)((char*)d_ws + (4u << 20));
    float* possum = expsum + 4096;
    float* out = (float*)d_out;

    nrm_kernel<<<1024, 256, 0, stream>>>(z, zn, expsum);
    gemm_kernel<<<656, 256, 0, stream>>>(zn, expsum, possum);   // 528 sym + 128 pos
    fin_kernel<<<1, 1024, 0, stream>>>(expsum, possum, out);
}

// Round 4
// 108.308 us; speedup vs baseline: 1.0062x; 1.0062x over previous
//
#include <hip/hip_runtime.h>
#include <hip/hip_bf16.h>

typedef __bf16 bf16x8 __attribute__((ext_vector_type(8)));
typedef float f32x16 __attribute__((ext_vector_type(16)));
typedef unsigned int u32x4 __attribute__((ext_vector_type(4)));
typedef unsigned short u16;

// Problem constants: T=16, N=128, D=512, M=4096, NT=2048, TEMP=0.1
// ws layout: zn bf16[4096*512] (4 MiB) | expsum f32[4096] | possum f32[4096]

// ---------------------------------------------------------------- normalize
// 1024 blocks x 256 threads; one wave per row, full-wave shfl_xor reduce,
// no LDS, no barrier. Also zeroes expsum.
__global__ void nrm_kernel(const float* __restrict__ z, u16* __restrict__ zn,
                           float* __restrict__ expsum) {
    int tid = threadIdx.x;
    int l = tid & 63, w = tid >> 6;
    int row = blockIdx.x * 4 + w;
    const float4* src = (const float4*)(z + row * 512);
    float4 v0 = src[l];
    float4 v1 = src[l + 64];
    float ss = v0.x * v0.x + v0.y * v0.y + v0.z * v0.z + v0.w * v0.w
             + v1.x * v1.x + v1.y * v1.y + v1.z * v1.z + v1.w * v1.w;
#pragma unroll
    for (int off = 32; off; off >>= 1) ss += __shfl_xor(ss, off, 64);
    float sc = 1.0f / fmaxf(sqrtf(ss), 1e-8f);   // matches ref clamp
    __hip_bfloat16 b0[4], b1[4];
    b0[0] = __float2bfloat16(v0.x * sc); b0[1] = __float2bfloat16(v0.y * sc);
    b0[2] = __float2bfloat16(v0.z * sc); b0[3] = __float2bfloat16(v0.w * sc);
    b1[0] = __float2bfloat16(v1.x * sc); b1[1] = __float2bfloat16(v1.y * sc);
    b1[2] = __float2bfloat16(v1.z * sc); b1[3] = __float2bfloat16(v1.w * sc);
    uint2 p0, p1;
    __builtin_memcpy(&p0, b0, 8);
    __builtin_memcpy(&p1, b1, 8);
    ((uint2*)(zn + row * 512))[l] = p0;
    ((uint2*)(zn + row * 512))[l + 64] = p1;
    int gi = blockIdx.x * 256 + tid;
    if (gi < 4096) expsum[gi] = 0.f;
}

// ------------------------------------------- symmetric GEMM (+pos tail)
// Blocks [0,528): triangular (ti<=tj) 128x128 tiles of the symmetric Gram.
//   4 waves/WG, wave owns 32 rows, A (32x512 bf16) resident in 128 VGPRs
//   (launch_bounds(256,1): VGPR cap 512 -> NO SPILL; r3's 48us was spill).
//   B col-tiles of 32 staged via global_load_lds width=16 into a K-MAJOR
//   LDS layout: granule G = kc*64 + (l>>5)*32 + (l&31). gll instr j lane l
//   writes G=64j+l linearly; the per-lane GLOBAL source supplies global
//   granule (l>>5)+2j of col l&31 (both-sides rule #21). The ds_read at
//   MFMA step kc is then LANE-LINEAR (byte = kc*1024 + lane*16): zero bank
//   conflicts, zero swizzle VALU, immediate offsets only.
//   Double-buffered, one barrier per col-tile; vmcnt(0) drain sits after
//   the 32-MFMA cluster. Off-diag tiles: e_ij feeds expsum[i] (row reduce)
//   AND expsum[j] (atomic, symmetry). Diag: rows only, diagonal masked in
//   the aligned (wave==ct) sub-block.
// Blocks [528,656): pos work — 32x32 group Gram, possum[i] = 10*sum dot.
__global__ __launch_bounds__(256, 1) void gemm_kernel(const u16* __restrict__ zn,
                                                      float* __restrict__ expsum,
                                                      float* __restrict__ possum) {
    __shared__ u16 Bt[2][32 * 512];            // 64 KiB double buffer

    int tid = threadIdx.x;
    int wave = tid >> 6;
    int l = tid & 63;
    int m = l & 31, h = l >> 5;

    if (blockIdx.x >= 528) {       // ---------------- positives tail
        if (tid < 64) {
            int g = blockIdx.x - 528;
            int grow = (m < 16) ? (g * 16 + m) : (2048 + g * 16 + (m - 16));
            const u32x4* src = (const u32x4*)(zn + grow * 512);
            f32x16 acc = {};
#pragma unroll
            for (int kc = 0; kc < 32; ++kc) {
                bf16x8 f = __builtin_bit_cast(bf16x8, src[h + 2 * kc]);
                acc = __builtin_amdgcn_mfma_f32_32x32x16_bf16(f, f, acc, 0, 0, 0);
            }
#pragma unroll
            for (int r = 0; r < 16; ++r) {
                int rrow = (r & 3) + 8 * (r >> 2) + 4 * h;
                float v = (rrow == m) ? 0.f : acc[r];
                v += __shfl_xor(v, 1, 64);
                v += __shfl_xor(v, 2, 64);
                v += __shfl_xor(v, 4, 64);
                v += __shfl_xor(v, 8, 64);
                v += __shfl_xor(v, 16, 64);
                if (m == 0) {
                    int gr = (rrow < 16) ? (g * 16 + rrow) : (2048 + g * 16 + (rrow - 16));
                    possum[gr] = v * 10.0f;   // plain store; fin is a separate launch
                }
            }
        }
        return;
    }

    // triangular decode: tile row ti has 32-ti tiles (tj = ti..31)
    int b = blockIdx.x;
    int ti = 0;
    while (b >= 32 - ti) { b -= 32 - ti; ++ti; }
    int tj = ti + b;

    int rowbase = ti * 128 + wave * 32;
    int colbase = tj * 128;
    bool diag = (ti == tj);

    // A fragments, full K=512: row rowbase+m, k-granule h+2*kc
    u32x4 a[32];
    const u32x4* arow = (const u32x4*)(zn + (rowbase + m) * 512);
#pragma unroll
    for (int kc = 0; kc < 32; ++kc) a[kc] = arow[h + 2 * kc];

    float racc[16];
#pragma unroll
    for (int r = 0; r < 16; ++r) racc[r] = 0.f;

    // stage: wave w issues j=w*8..w*8+7; gll writes LDS granules [64j,64j+64)
    // linearly; lane l sources col (l&31), global granule (l>>5)+2j.
#define STAGE(bufidx, cb)                                                          \
    {                                                                              \
        u16* buf_ = (u16*)Bt[bufidx];                                              \
        _Pragma("unroll")                                                          \
        for (int i_ = 0; i_ < 8; ++i_) {                                           \
            int j_ = wave * 8 + i_;                                                \
            const u16* gsrc_ = zn + ((cb) + (l & 31)) * 512 + ((l >> 5) + 2 * j_) * 8; \
            __builtin_amdgcn_global_load_lds(                                      \
                (const __attribute__((address_space(1))) unsigned int*)gsrc_,      \
                (__attribute__((address_space(3))) unsigned int*)(buf_ + j_ * 512), \
                16, 0, 0);                                                         \
        }                                                                          \
    }

    STAGE(0, colbase)
    __syncthreads();           // implicit vmcnt(0): tile 0 landed

    for (int ct = 0; ct < 4; ++ct) {
        if (ct < 3) STAGE((ct + 1) & 1, colbase + (ct + 1) * 32)
        const char* rb = (const char*)Bt[ct & 1] + l * 16;   // lane-linear base
        f32x16 acc = {};
        __builtin_amdgcn_s_setprio(1);
#pragma unroll
        for (int kc = 0; kc < 32; ++kc) {
            bf16x8 bf = *(const bf16x8*)(rb + kc * 1024);    // conflict-free
            acc = __builtin_amdgcn_mfma_f32_32x32x16_bf16(
                __builtin_bit_cast(bf16x8, a[kc]), bf, acc, 0, 0, 0);
        }
        __builtin_amdgcn_s_setprio(0);

        if (diag && ct == wave) {  // aligned sub-block: mask true diagonal
#pragma unroll
            for (int r = 0; r < 16; ++r) {
                int rrow = (r & 3) + 8 * (r >> 2) + 4 * h;
                if (rrow != m) racc[r] += __builtin_exp2f(acc[r] * 14.426950408889634f);
            }
        } else {
            float csum = 0.f;
#pragma unroll
            for (int r = 0; r < 16; ++r) {
                float e = __builtin_exp2f(acc[r] * 14.426950408889634f);
                racc[r] += e;
                csum += e;
            }
            if (!diag) {           // symmetric contribution to the col rows
                csum += __shfl_xor(csum, 32, 64);   // combine the two k-halves
                if (h == 0) atomicAdd(&expsum[colbase + ct * 32 + m], csum);
            }
        }
        __syncthreads();           // next tile landed; current reads done
    }

    // row sums: reduce over the 32 cols held in lanes of each half
#pragma unroll
    for (int r = 0; r < 16; ++r) {
        float v = racc[r];
        v += __shfl_xor(v, 1, 64);
        v += __shfl_xor(v, 2, 64);
        v += __shfl_xor(v, 4, 64);
        v += __shfl_xor(v, 8, 64);
        v += __shfl_xor(v, 16, 64);
        if (m == 0) {
            int rrow = (r & 3) + 8 * (r >> 2) + 4 * h;
            atomicAdd(&expsum[rowbase + rrow], v);
        }
    }
}

// ---------------------------------------------------------------- finalize
__global__ void fin_kernel(const float* __restrict__ expsum,
                           const float* __restrict__ possum, float* __restrict__ out) {
    int tid = threadIdx.x;         // 1024
    float s = 0.f;
    for (int i = tid; i < 4096; i += 1024)
        s += __logf(expsum[i]) - possum[i] * (1.0f / 31.0f);
#pragma unroll
    for (int off = 32; off; off >>= 1) s += __shfl_down(s, off, 64);
    __shared__ float red[16];
    if ((tid & 63) == 0) red[tid >> 6] = s;
    __syncthreads();
    if (tid == 0) {
        float t = 0.f;
#pragma unroll
        for (int i = 0; i < 16; ++i) t += red[i];
        out[0] = t * (1.0f / 4096.0f);
    }
}

extern "C" void kernel_launch(void* const* d_in, const int* in_sizes, int n_in,
                              void* d_out, int out_size, void* d_ws, size_t ws_size,
                              hipStream_t stream) {
    const float* z = (const float*)d_in[0];
    // d_in[1] (done) is provably dead: positive_mask reduces to block-diag + eye.
    u16* zn = (u16*)d_ws;
    float* expsum = (float*)((char*)d_ws + (4u << 20));
    float* possum = expsum + 4096;
    float* out = (float*)d_out;

    nrm_kernel<<<1024, 256, 0, stream>>>(z, zn, expsum);
    gemm_kernel<<<656, 256, 0, stream>>>(zn, expsum, possum);   // 528 sym + 128 pos
    fin_kernel<<<1, 1024, 0, stream>>>(expsum, possum, out);
}

// Round 5
// 106.631 us; speedup vs baseline: 1.0220x; 1.0157x over previous
//
#include <hip/hip_runtime.h>
#include <hip/hip_bf16.h>

typedef __bf16 bf16x8 __attribute__((ext_vector_type(8)));
typedef float f32x16 __attribute__((ext_vector_type(16)));
typedef unsigned int u32x4 __attribute__((ext_vector_type(4)));
typedef unsigned short u16;

// Problem constants: T=16, N=128, D=512, M=4096, NT=2048, TEMP=0.1
// ws layout: zn bf16[4096*512] (4 MiB) | expsum f32[4096] | possum f32[4096]

// ---------------------------------------------------------------- normalize
// 1024 blocks x 256 threads; one wave per row, full-wave shfl_xor reduce,
// no LDS, no barrier. Also zeroes expsum.
__global__ void nrm_kernel(const float* __restrict__ z, u16* __restrict__ zn,
                           float* __restrict__ expsum) {
    int tid = threadIdx.x;
    int l = tid & 63, w = tid >> 6;
    int row = blockIdx.x * 4 + w;
    const float4* src = (const float4*)(z + row * 512);
    float4 v0 = src[l];
    float4 v1 = src[l + 64];
    float ss = v0.x * v0.x + v0.y * v0.y + v0.z * v0.z + v0.w * v0.w
             + v1.x * v1.x + v1.y * v1.y + v1.z * v1.z + v1.w * v1.w;
#pragma unroll
    for (int off = 32; off; off >>= 1) ss += __shfl_xor(ss, off, 64);
    float sc = 1.0f / fmaxf(sqrtf(ss), 1e-8f);   // matches ref clamp
    __hip_bfloat16 b0[4], b1[4];
    b0[0] = __float2bfloat16(v0.x * sc); b0[1] = __float2bfloat16(v0.y * sc);
    b0[2] = __float2bfloat16(v0.z * sc); b0[3] = __float2bfloat16(v0.w * sc);
    b1[0] = __float2bfloat16(v1.x * sc); b1[1] = __float2bfloat16(v1.y * sc);
    b1[2] = __float2bfloat16(v1.z * sc); b1[3] = __float2bfloat16(v1.w * sc);
    uint2 p0, p1;
    __builtin_memcpy(&p0, b0, 8);
    __builtin_memcpy(&p1, b1, 8);
    ((uint2*)(zn + row * 512))[l] = p0;
    ((uint2*)(zn + row * 512))[l + 64] = p1;
    int gi = blockIdx.x * 256 + tid;
    if (gi < 4096) expsum[gi] = 0.f;
}

// ------------------------------------------- symmetric GEMM (+pos tail)
// Blocks [0,528): triangular (ti<=tj) 128x128 tiles of the symmetric Gram.
//   4 waves/WG, wave owns 32 rows, A (32x512 bf16) resident in 128 VGPRs
//   (launch_bounds(256,1): no spill). B col-tiles staged via global_load_lds
//   width=16 into K-major LDS (granule G = kc*64 + lane): ds_read at step kc
//   is lane-linear -> zero bank conflicts, zero swizzle VALU.
//   Double-buffered, one barrier per col-tile.
//   KEY (r4 post-mortem): NO atomics inside the barrier loop. Symmetric
//   column contributions accumulate in registers (colacc[4], static index),
//   cross-wave reduced through LDS after the loop, then 128 end-of-block
//   atomics. r4's 47.5us was barrier-coupled contended-atomic stall
//   (vmcnt(0) at __syncthreads drains the RMW acks).
// Blocks [528,656): pos work — 32x32 group Gram, possum[i] = 10*sum dot.
__global__ __launch_bounds__(256, 1) void gemm_kernel(const u16* __restrict__ zn,
                                                      float* __restrict__ expsum,
                                                      float* __restrict__ possum) {
    __shared__ u16 Bt[2][32 * 512];            // 64 KiB double buffer

    int tid = threadIdx.x;
    int wave = tid >> 6;
    int l = tid & 63;
    int m = l & 31, h = l >> 5;

    if (blockIdx.x >= 528) {       // ---------------- positives tail
        if (tid < 64) {
            int g = blockIdx.x - 528;
            int grow = (m < 16) ? (g * 16 + m) : (2048 + g * 16 + (m - 16));
            const u32x4* src = (const u32x4*)(zn + grow * 512);
            f32x16 acc = {};
#pragma unroll
            for (int kc = 0; kc < 32; ++kc) {
                bf16x8 f = __builtin_bit_cast(bf16x8, src[h + 2 * kc]);
                acc = __builtin_amdgcn_mfma_f32_32x32x16_bf16(f, f, acc, 0, 0, 0);
            }
#pragma unroll
            for (int r = 0; r < 16; ++r) {
                int rrow = (r & 3) + 8 * (r >> 2) + 4 * h;
                float v = (rrow == m) ? 0.f : acc[r];
                v += __shfl_xor(v, 1, 64);
                v += __shfl_xor(v, 2, 64);
                v += __shfl_xor(v, 4, 64);
                v += __shfl_xor(v, 8, 64);
                v += __shfl_xor(v, 16, 64);
                if (m == 0) {
                    int gr = (rrow < 16) ? (g * 16 + rrow) : (2048 + g * 16 + (rrow - 16));
                    possum[gr] = v * 10.0f;   // plain store; fin is a separate launch
                }
            }
        }
        return;
    }

    // triangular decode: tile row ti has 32-ti tiles (tj = ti..31)
    int b = blockIdx.x;
    int ti = 0;
    while (b >= 32 - ti) { b -= 32 - ti; ++ti; }
    int tj = ti + b;

    int rowbase = ti * 128 + wave * 32;
    int colbase = tj * 128;
    bool diag = (ti == tj);

    // A fragments, full K=512: row rowbase+m, k-granule h+2*kc
    u32x4 a[32];
    const u32x4* arow = (const u32x4*)(zn + (rowbase + m) * 512);
#pragma unroll
    for (int kc = 0; kc < 32; ++kc) a[kc] = arow[h + 2 * kc];

    float racc[16];
#pragma unroll
    for (int r = 0; r < 16; ++r) racc[r] = 0.f;
    float colacc[4] = {0.f, 0.f, 0.f, 0.f};    // per-lane column partials (static idx)

    // stage: wave w issues j=w*8..w*8+7; gll writes LDS granules [64j,64j+64)
    // linearly; lane l sources col (l&31), global granule (l>>5)+2j.
#define STAGE(bufidx, cb)                                                          \
    {                                                                              \
        u16* buf_ = (u16*)Bt[bufidx];                                              \
        _Pragma("unroll")                                                          \
        for (int i_ = 0; i_ < 8; ++i_) {                                           \
            int j_ = wave * 8 + i_;                                                \
            const u16* gsrc_ = zn + ((cb) + (l & 31)) * 512 + ((l >> 5) + 2 * j_) * 8; \
            __builtin_amdgcn_global_load_lds(                                      \
                (const __attribute__((address_space(1))) unsigned int*)gsrc_,      \
                (__attribute__((address_space(3))) unsigned int*)(buf_ + j_ * 512), \
                16, 0, 0);                                                         \
        }                                                                          \
    }

    STAGE(0, colbase)
    __syncthreads();           // implicit vmcnt(0): tile 0 landed

#pragma unroll
    for (int ct = 0; ct < 4; ++ct) {
        if (ct < 3) STAGE((ct + 1) & 1, colbase + (ct + 1) * 32)
        const char* rb = (const char*)Bt[ct & 1] + l * 16;   // lane-linear base
        f32x16 acc = {};
        __builtin_amdgcn_s_setprio(1);
#pragma unroll
        for (int kc = 0; kc < 32; ++kc) {
            bf16x8 bf = *(const bf16x8*)(rb + kc * 1024);    // conflict-free
            acc = __builtin_amdgcn_mfma_f32_32x32x16_bf16(
                __builtin_bit_cast(bf16x8, a[kc]), bf, acc, 0, 0, 0);
        }
        __builtin_amdgcn_s_setprio(0);

        if (diag && ct == wave) {  // aligned sub-block: mask true diagonal
#pragma unroll
            for (int r = 0; r < 16; ++r) {
                int rrow = (r & 3) + 8 * (r >> 2) + 4 * h;
                if (rrow != m) racc[r] += __builtin_exp2f(acc[r] * 14.426950408889634f);
            }
        } else {
            float csum = 0.f;
#pragma unroll
            for (int r = 0; r < 16; ++r) {
                float e = __builtin_exp2f(acc[r] * 14.426950408889634f);
                racc[r] += e;
                csum += e;
            }
            colacc[ct] += csum;    // register only; no VMEM in the loop
        }
        __syncthreads();           // next tile landed; current reads done
    }

    // row sums: reduce over the 32 cols held in lanes of each half
#pragma unroll
    for (int r = 0; r < 16; ++r) {
        float v = racc[r];
        v += __shfl_xor(v, 1, 64);
        v += __shfl_xor(v, 2, 64);
        v += __shfl_xor(v, 4, 64);
        v += __shfl_xor(v, 8, 64);
        v += __shfl_xor(v, 16, 64);
        if (m == 0) {
            int rrow = (r & 3) + 8 * (r >> 2) + 4 * h;
            atomicAdd(&expsum[rowbase + rrow], v);
        }
    }

    // symmetric column sums: cross-wave reduce via LDS (Bt is dead after the
    // loop's final barrier), then one atomic per column, end-of-kernel only.
    if (!diag) {
        float* colred = (float*)Bt;            // [4 waves][128 cols]
#pragma unroll
        for (int ct = 0; ct < 4; ++ct) {
            float v = colacc[ct] + __shfl_xor(colacc[ct], 32, 64);  // combine k-halves
            if (h == 0) colred[wave * 128 + ct * 32 + m] = v;
        }
        __syncthreads();
        if (tid < 128) {
            float s = colred[tid] + colred[128 + tid] + colred[256 + tid] + colred[384 + tid];
            atomicAdd(&expsum[colbase + tid], s);
        }
    }
}

// ---------------------------------------------------------------- finalize
__global__ void fin_kernel(const float* __restrict__ expsum,
                           const float* __restrict__ possum, float* __restrict__ out) {
    int tid = threadIdx.x;         // 1024
    float s = 0.f;
    for (int i = tid; i < 4096; i += 1024)
        s += __logf(expsum[i]) - possum[i] * (1.0f / 31.0f);
#pragma unroll
    for (int off = 32; off; off >>= 1) s += __shfl_down(s, off, 64);
    __shared__ float red[16];
    if ((tid & 63) == 0) red[tid >> 6] = s;
    __syncthreads();
    if (tid == 0) {
        float t = 0.f;
#pragma unroll
        for (int i = 0; i < 16; ++i) t += red[i];
        out[0] = t * (1.0f / 4096.0f);
    }
}

extern "C" void kernel_launch(void* const* d_in, const int* in_sizes, int n_in,
                              void* d_out, int out_size, void* d_ws, size_t ws_size,
                              hipStream_t stream) {
    const float* z = (const float*)d_in[0];
    // d_in[1] (done) is provably dead: positive_mask reduces to block-diag + eye.
    u16* zn = (u16*)d_ws;
    float* expsum = (float*)((char*)d_ws + (4u << 20));
    float* possum = expsum + 4096;
    float* out = (float*)d_out;

    nrm_kernel<<<1024, 256, 0, stream>>>(z, zn, expsum);
    gemm_kernel<<<656, 256, 0, stream>>>(zn, expsum, possum);   // 528 sym + 128 pos
    fin_kernel<<<1, 1024, 0, stream>>>(expsum, possum, out);
}